// Round 3
// baseline (147.612 us; speedup 1.0000x reference)
//
#include <hip/hip_runtime.h>
#include <hip/hip_bf16.h>

// Problem constants (features: (16, 1024, 512) fp32)
#define B_ 16
#define T_ 1024
#define D_ 512
#define EPS_ 1e-8f
#define SCALE2 20.609929155566063f   // (1/0.07) * log2(e): logits in base-2 domain
#define LN2_ 0.6931471805599453f

#define BM 128
#define BN 128
#define NB 8               // T_/BM block-rows per batch
#define NKIT 16            // D_/32 K-iterations (BK=32 bf16)

typedef __attribute__((ext_vector_type(8))) short short8;   // 8 bf16 = 4 VGPRs
typedef __attribute__((ext_vector_type(4))) float floatx4;

__device__ __forceinline__ unsigned short f2bf(float x) {
    unsigned u = __float_as_uint(x);
    return (unsigned short)((u + 0x7fffu + ((u >> 16) & 1u)) >> 16);  // RNE
}

// ---------------- row L2-normalize -> bf16, fused zero-init ------------------
// grid 4096 x 256: one wave per row; first 64 blocks also zero rs/rp/out.
__global__ __launch_bounds__(256) void norm_kernel(const float* __restrict__ f,
                                                   unsigned short* __restrict__ nrm,
                                                   float* __restrict__ rs_g,
                                                   float* __restrict__ rp_g,
                                                   float* __restrict__ out) {
    const int gi = blockIdx.x * 256 + threadIdx.x;
    if (gi < B_ * T_) { rs_g[gi] = 0.0f; rp_g[gi] = 0.0f; }
    if (gi == 0) out[0] = 0.0f;

    const int row  = blockIdx.x * 4 + (threadIdx.x >> 6);
    const int lane = threadIdx.x & 63;
    const size_t off = (size_t)row * D_ + lane * 8;
    const float4 v0 = *(const float4*)(f + off);
    const float4 v1 = *(const float4*)(f + off + 4);
    float ss = v0.x*v0.x + v0.y*v0.y + v0.z*v0.z + v0.w*v0.w
             + v1.x*v1.x + v1.y*v1.y + v1.z*v1.z + v1.w*v1.w;
    #pragma unroll
    for (int o = 32; o >= 1; o >>= 1) ss += __shfl_xor(ss, o, 64);
    const float sc = 1.0f / fmaxf(sqrtf(ss), EPS_);
    ushort4 w0, w1;
    w0.x = f2bf(v0.x*sc); w0.y = f2bf(v0.y*sc); w0.z = f2bf(v0.z*sc); w0.w = f2bf(v0.w*sc);
    w1.x = f2bf(v1.x*sc); w1.y = f2bf(v1.y*sc); w1.z = f2bf(v1.z*sc); w1.w = f2bf(v1.w*sc);
    *(ushort4*)(nrm + off)     = w0;
    *(ushort4*)(nrm + off + 4) = w1;
}

// ---------------- MFMA sim-GEMM, symmetric upper-triangle, no LDS -----------
// grid (36, 16): blockIdx.x -> upper-triangle block pair (bi<=bj), blockIdx.y=b.
// Both MFMA operands are rows of the same row-major matrix (sim = N*N^T), so
// A and B fragments load DIRECTLY from global in MFMA layout: no LDS, no
// barriers -> compiler pipelines loads with fine-grained vmcnt.
// Off-diagonal blocks contribute row sums (anchors t in I) AND col sums
// (anchors j in J, negatives t in I) -- the mask |j-t|<=1 is symmetric.
__global__ __launch_bounds__(256) void loss_kernel(const unsigned short* __restrict__ nrm,
                                                   float* __restrict__ rs_g,
                                                   float* __restrict__ rp_g) {
    // decode upper-triangle pair (bi, bj)
    int u = blockIdx.x, bi = 0, rem = NB;
    while (u >= rem) { u -= rem; --rem; ++bi; }
    const int bj   = bi + u;
    const bool diag = (bi == bj);

    const int b  = blockIdx.y;
    const int t0 = bi * BM;
    const int j0 = bj * BN;
    const unsigned short* base = nrm + (size_t)b * T_ * D_;

    const int tid  = threadIdx.x;
    const int w    = tid >> 6;
    const int lane = tid & 63;
    const int wr   = w >> 1;          // wave quadrant row (0..1)
    const int wc   = w & 1;           // wave quadrant col (0..1)
    const int m    = lane & 15;       // fragment row/col lane
    const int kq   = lane >> 4;       // k-group: k = kq*8 + j

    // per-lane fragment base pointers (16B-aligned; kit*64B fits imm offset)
    const unsigned short* pA[4];
    const unsigned short* pB[4];
    #pragma unroll
    for (int i = 0; i < 4; ++i) {
        pA[i] = base + (size_t)(t0 + wr * 64 + i * 16 + m) * D_ + kq * 8;
        pB[i] = base + (size_t)(j0 + wc * 64 + i * 16 + m) * D_ + kq * 8;
    }

    floatx4 acc[4][4] = {};
    short8 af[2][4], bf[2][4];
    #pragma unroll
    for (int i = 0; i < 4; ++i) {
        af[0][i] = *(const short8*)(pA[i]);
        bf[0][i] = *(const short8*)(pB[i]);
    }

    #pragma unroll
    for (int kit = 0; kit < NKIT; ++kit) {
        const int cur = kit & 1, nxt = cur ^ 1;
        if (kit + 1 < NKIT) {
            #pragma unroll
            for (int i = 0; i < 4; ++i) {
                af[nxt][i] = *(const short8*)(pA[i] + (kit + 1) * 32);
                bf[nxt][i] = *(const short8*)(pB[i] + (kit + 1) * 32);
            }
        }
        #pragma unroll
        for (int mi = 0; mi < 4; ++mi)
            #pragma unroll
            for (int ni = 0; ni < 4; ++ni)
                acc[mi][ni] = __builtin_amdgcn_mfma_f32_16x16x32_bf16(
                    af[cur][mi], bf[cur][ni], acc[mi][ni], 0, 0, 0);
    }

    // Epilogue. C/D layout (m89-verified): col = lane&15, row = (lane>>4)*4 + reg.
    const int lrow = lane >> 4;
    const int lcol = lane & 15;
    const int bT   = b * T_;
    float cs[4] = {0.f, 0.f, 0.f, 0.f};   // per-ni column partial sums (off-diag)

    #pragma unroll
    for (int mi = 0; mi < 4; ++mi) {
        #pragma unroll
        for (int r = 0; r < 4; ++r) {
            const int t = t0 + wr * 64 + mi * 16 + lrow * 4 + r;
            float rsum = 0.f;
            #pragma unroll
            for (int ni = 0; ni < 4; ++ni) {
                const int j  = j0 + wc * 64 + ni * 16 + lcol;
                const float s2 = acc[mi][ni][r] * SCALE2;       // base-2 logit
                const float e  = exp2f(s2);
                if (j < t - 1 || j > t + 1) { rsum += e; cs[ni] += e; }
                if (j == t + 1) atomicAdd(&rp_g[bT + t], s2);   // unique owner
            }
            #pragma unroll
            for (int o = 8; o >= 1; o >>= 1) rsum += __shfl_xor(rsum, o, 64);
            if (lcol == 0) atomicAdd(&rs_g[bT + t], rsum);
        }
    }
    if (!diag) {
        #pragma unroll
        for (int ni = 0; ni < 4; ++ni) {
            float c = cs[ni];
            c += __shfl_xor(c, 16, 64);
            c += __shfl_xor(c, 32, 64);
            if (lrow == 0)
                atomicAdd(&rs_g[bT + j0 + wc * 64 + ni * 16 + lcol], c);
        }
    }
}

// ---------------- finalize: loss per (b,t), mean (base-2 domain) -------------
__global__ __launch_bounds__(256) void fin_kernel(const float* __restrict__ rs_g,
                                                  const float* __restrict__ rp_g,
                                                  float* __restrict__ out) {
    const int idx = blockIdx.x * 256 + threadIdx.x;
    float v = 0.0f;
    if (idx < B_ * T_) {
        const int t = idx & (T_ - 1);
        if (t >= 1 && t <= T_ - 2) {
            const float p2 = rp_g[idx];           // pos logit * log2e
            const float s  = rs_g[idx];           // sum_neg 2^logit2
            v = (log2f(exp2f(p2) + s) - p2) * LN2_;
        }
    }
    #pragma unroll
    for (int o = 32; o >= 1; o >>= 1) v += __shfl_xor(v, o, 64);
    __shared__ float ws_[4];
    if ((threadIdx.x & 63) == 0) ws_[threadIdx.x >> 6] = v;
    __syncthreads();
    if (threadIdx.x == 0) {
        const float scale = 1.0f / (float)(B_ * (T_ - 2));
        atomicAdd(out, (ws_[0] + ws_[1] + ws_[2] + ws_[3]) * scale);
    }
}

extern "C" void kernel_launch(void* const* d_in, const int* in_sizes, int n_in,
                              void* d_out, int out_size, void* d_ws, size_t ws_size,
                              hipStream_t stream) {
    const float* feat = (const float*)d_in[0];
    float* out = (float*)d_out;

    // ws layout: nrm (bf16, B*T*D ushorts = 16 MB) | rs (B*T f32) | rp (B*T f32)
    unsigned short* nrm = (unsigned short*)d_ws;
    float* rs_g = (float*)((char*)d_ws + (size_t)B_ * T_ * D_ * sizeof(unsigned short));
    float* rp_g = rs_g + B_ * T_;

    norm_kernel<<<B_ * T_ / 4, 256, 0, stream>>>(feat, nrm, rs_g, rp_g, out);
    loss_kernel<<<dim3(NB * (NB + 1) / 2, B_), 256, 0, stream>>>(nrm, rs_g, rp_g);
    fin_kernel<<<(B_ * T_ + 255) / 256, 256, 0, stream>>>(rs_g, rp_g, out);
}

// Round 4
// 125.195 us; speedup vs baseline: 1.1791x; 1.1791x over previous
//
#include <hip/hip_runtime.h>
#include <hip/hip_bf16.h>

// Problem constants (features: (16, 1024, 512) fp32)
#define B_ 16
#define T_ 1024
#define D_ 512
#define EPS_ 1e-8f
#define SCALE2 20.609929155566063f   // (1/0.07) * log2(e): logits in base-2 domain
#define LN2_ 0.6931471805599453f

#define BT 64              // tile side per wave
#define NB 16              // T_/BT block-rows per batch
#define NPAIR (NB * (NB + 1) / 2)   // 136 upper-triangle pairs
#define NKIT 16            // D_/32 K-iterations (BK=32 bf16)

typedef __attribute__((ext_vector_type(8))) short short8;   // 8 bf16 = 4 VGPRs
typedef __attribute__((ext_vector_type(4))) float floatx4;

__device__ __forceinline__ unsigned short f2bf(float x) {
    unsigned u = __float_as_uint(x);
    return (unsigned short)((u + 0x7fffu + ((u >> 16) & 1u)) >> 16);  // RNE
}

// ---------------- row L2-normalize -> bf16, fused zero-init ------------------
__global__ __launch_bounds__(256) void norm_kernel(const float* __restrict__ f,
                                                   unsigned short* __restrict__ nrm,
                                                   float* __restrict__ rs_g,
                                                   float* __restrict__ rp_g,
                                                   float* __restrict__ out) {
    const int gi = blockIdx.x * 256 + threadIdx.x;
    if (gi < B_ * T_) { rs_g[gi] = 0.0f; rp_g[gi] = 0.0f; }
    if (gi == 0) out[0] = 0.0f;

    const int row  = blockIdx.x * 4 + (threadIdx.x >> 6);
    const int lane = threadIdx.x & 63;
    const size_t off = (size_t)row * D_ + lane * 8;
    const float4 v0 = *(const float4*)(f + off);
    const float4 v1 = *(const float4*)(f + off + 4);
    float ss = v0.x*v0.x + v0.y*v0.y + v0.z*v0.z + v0.w*v0.w
             + v1.x*v1.x + v1.y*v1.y + v1.z*v1.z + v1.w*v1.w;
    #pragma unroll
    for (int o = 32; o >= 1; o >>= 1) ss += __shfl_xor(ss, o, 64);
    const float sc = 1.0f / fmaxf(sqrtf(ss), EPS_);
    ushort4 w0, w1;
    w0.x = f2bf(v0.x*sc); w0.y = f2bf(v0.y*sc); w0.z = f2bf(v0.z*sc); w0.w = f2bf(v0.w*sc);
    w1.x = f2bf(v1.x*sc); w1.y = f2bf(v1.y*sc); w1.z = f2bf(v1.z*sc); w1.w = f2bf(v1.w*sc);
    *(ushort4*)(nrm + off)     = w0;
    *(ushort4*)(nrm + off + 4) = w1;
}

// ---------------- MFMA sim-GEMM: 1 wave = 64x64 tile, no LDS, sym ------------
// grid: 1-D, NPAIR*16 blocks of 64 threads. Block id -> (pair, batch) with the
// batch placed so id%8 (the XCD round-robin heuristic) pins each batch to one
// XCD: per-XCD working set = 2 batches = 2 MB, L2-resident.
// sim = N*N^T with N row-major, so A and B fragments are identical-layout row
// reads -> direct global loads, no transpose, no LDS, no barriers.
// Depth-2 rotating register prefetch covers ~200cyc L2 latency.
__global__ __launch_bounds__(64) void loss_kernel(const unsigned short* __restrict__ nrm,
                                                  float* __restrict__ rs_g,
                                                  float* __restrict__ rp_g) {
    const int slot = blockIdx.x & 15;
    int u = blockIdx.x >> 4;                 // pair index 0..135
    const int b = ((slot & 7) << 1) | (slot >> 3);
    int bi = 0, rem = NB;
    while (u >= rem) { u -= rem; --rem; ++bi; }
    const int bj = bi + u;
    const bool diag = (bi == bj);

    const int t0 = bi * BT;
    const int j0 = bj * BT;
    const unsigned short* base = nrm + (size_t)b * T_ * D_;

    const int lane = threadIdx.x & 63;
    const int m    = lane & 15;       // fragment row lane
    const int kq   = lane >> 4;       // k-group: k = kq*8 + j

    const unsigned short* pA[4];
    const unsigned short* pB[4];
    #pragma unroll
    for (int i = 0; i < 4; ++i) {
        pA[i] = base + (size_t)(t0 + i * 16 + m) * D_ + kq * 8;
        pB[i] = base + (size_t)(j0 + i * 16 + m) * D_ + kq * 8;
    }

    floatx4 acc[4][4] = {};
    short8 af[3][4], bf[3][4];        // 3-slot rotating prefetch buffers

    #pragma unroll
    for (int s = 0; s < 2; ++s) {     // prologue: kits 0,1 in flight
        #pragma unroll
        for (int i = 0; i < 4; ++i) {
            af[s][i] = *(const short8*)(pA[i] + s * 32);
            bf[s][i] = *(const short8*)(pB[i] + s * 32);
        }
    }

    #pragma unroll
    for (int kit = 0; kit < NKIT; ++kit) {
        const int cur = kit % 3;
        if (kit + 2 < NKIT) {
            const int nx2 = (kit + 2) % 3;
            #pragma unroll
            for (int i = 0; i < 4; ++i) {
                af[nx2][i] = *(const short8*)(pA[i] + (kit + 2) * 32);
                bf[nx2][i] = *(const short8*)(pB[i] + (kit + 2) * 32);
            }
        }
        #pragma unroll
        for (int mi = 0; mi < 4; ++mi)
            #pragma unroll
            for (int ni = 0; ni < 4; ++ni)
                acc[mi][ni] = __builtin_amdgcn_mfma_f32_16x16x32_bf16(
                    af[cur][mi], bf[cur][ni], acc[mi][ni], 0, 0, 0);
    }

    // Epilogue. C/D layout (m89-verified): col = lane&15, row = (lane>>4)*4+reg.
    const int lrow = lane >> 4;
    const int lcol = lane & 15;
    const int bT   = b * T_;
    float cs[4] = {0.f, 0.f, 0.f, 0.f};   // per-ni column partials (off-diag)

    #pragma unroll
    for (int mi = 0; mi < 4; ++mi) {
        #pragma unroll
        for (int r = 0; r < 4; ++r) {
            const int t = t0 + mi * 16 + lrow * 4 + r;
            float rsum = 0.f;
            #pragma unroll
            for (int ni = 0; ni < 4; ++ni) {
                const int j  = j0 + ni * 16 + lcol;
                const float s2 = acc[mi][ni][r] * SCALE2;       // base-2 logit
                const float e  = exp2f(s2);
                if (j < t - 1 || j > t + 1) { rsum += e; cs[ni] += e; }
                if (j == t + 1) atomicAdd(&rp_g[bT + t], s2);   // unique owner
            }
            #pragma unroll
            for (int o = 8; o >= 1; o >>= 1) rsum += __shfl_xor(rsum, o, 64);
            if (lcol == 0) atomicAdd(&rs_g[bT + t], rsum);
        }
    }
    if (!diag) {  // column sums: anchors j in J, negatives t in I (mask symmetric)
        #pragma unroll
        for (int ni = 0; ni < 4; ++ni) {
            float c = cs[ni];
            c += __shfl_xor(c, 16, 64);
            c += __shfl_xor(c, 32, 64);
            if (lrow == 0)
                atomicAdd(&rs_g[bT + j0 + ni * 16 + lcol], c);
        }
    }
}

// ---------------- finalize: loss per (b,t), mean (base-2 domain) -------------
__global__ __launch_bounds__(256) void fin_kernel(const float* __restrict__ rs_g,
                                                  const float* __restrict__ rp_g,
                                                  float* __restrict__ out) {
    const int idx = blockIdx.x * 256 + threadIdx.x;
    float v = 0.0f;
    if (idx < B_ * T_) {
        const int t = idx & (T_ - 1);
        if (t >= 1 && t <= T_ - 2) {
            const float p2 = rp_g[idx];           // pos logit * log2e
            const float s  = rs_g[idx];           // sum_neg 2^logit2
            v = (log2f(exp2f(p2) + s) - p2) * LN2_;
        }
    }
    #pragma unroll
    for (int o = 32; o >= 1; o >>= 1) v += __shfl_xor(v, o, 64);
    __shared__ float ws_[4];
    if ((threadIdx.x & 63) == 0) ws_[threadIdx.x >> 6] = v;
    __syncthreads();
    if (threadIdx.x == 0) {
        const float scale = 1.0f / (float)(B_ * (T_ - 2));
        atomicAdd(out, (ws_[0] + ws_[1] + ws_[2] + ws_[3]) * scale);
    }
}

extern "C" void kernel_launch(void* const* d_in, const int* in_sizes, int n_in,
                              void* d_out, int out_size, void* d_ws, size_t ws_size,
                              hipStream_t stream) {
    const float* feat = (const float*)d_in[0];
    float* out = (float*)d_out;

    // ws layout: nrm (bf16, B*T*D ushorts = 16 MB) | rs (B*T f32) | rp (B*T f32)
    unsigned short* nrm = (unsigned short*)d_ws;
    float* rs_g = (float*)((char*)d_ws + (size_t)B_ * T_ * D_ * sizeof(unsigned short));
    float* rp_g = rs_g + B_ * T_;

    norm_kernel<<<B_ * T_ / 4, 256, 0, stream>>>(feat, nrm, rs_g, rp_g, out);
    loss_kernel<<<NPAIR * B_, 64, 0, stream>>>(nrm, rs_g, rp_g);
    fin_kernel<<<(B_ * T_ + 255) / 256, 256, 0, stream>>>(rs_g, rp_g, out);
}

// Round 6
// 107.154 us; speedup vs baseline: 1.3776x; 1.1684x over previous
//
#include <hip/hip_runtime.h>
#include <hip/hip_bf16.h>

// Problem constants (features: (16, 1024, 512) fp32)
#define B_ 16
#define T_ 1024
#define D_ 512
#define EPS_ 1e-8f
#define SCALE2 20.609929155566063f   // (1/0.07) * log2(e): logits in base-2 domain
#define LN2_ 0.6931471805599453f

#define BM 128
#define BN 128
#define NKIT 16            // D_/32 K-iterations (BK=32 bf16 = 64 B/row)

typedef __attribute__((ext_vector_type(8))) short short8;   // 8 bf16 = 4 VGPRs
typedef __attribute__((ext_vector_type(4))) float floatx4;

typedef __attribute__((address_space(1))) const unsigned int g_u32;
typedef __attribute__((address_space(3))) unsigned int l_u32;

__device__ __forceinline__ void glds16(const void* g, void* l) {
    __builtin_amdgcn_global_load_lds((g_u32*)g, (l_u32*)l, 16, 0, 0);
}

__device__ __forceinline__ unsigned short f2bf(float x) {
    unsigned u = __float_as_uint(x);
    return (unsigned short)((u + 0x7fffu + ((u >> 16) & 1u)) >> 16);  // RNE
}

// ---------------- row L2-normalize -> bf16, fused zero-init ------------------
__global__ __launch_bounds__(256) void norm_kernel(const float* __restrict__ f,
                                                   unsigned short* __restrict__ nrm,
                                                   float* __restrict__ rs_g,
                                                   float* __restrict__ rp_g,
                                                   float* __restrict__ out) {
    const int gi = blockIdx.x * 256 + threadIdx.x;
    if (gi < B_ * T_) { rs_g[gi] = 0.0f; rp_g[gi] = 0.0f; }
    if (gi == 0) out[0] = 0.0f;

    const int row  = blockIdx.x * 4 + (threadIdx.x >> 6);
    const int lane = threadIdx.x & 63;
    const size_t off = (size_t)row * D_ + lane * 8;
    const float4 v0 = *(const float4*)(f + off);
    const float4 v1 = *(const float4*)(f + off + 4);
    float ss = v0.x*v0.x + v0.y*v0.y + v0.z*v0.z + v0.w*v0.w
             + v1.x*v1.x + v1.y*v1.y + v1.z*v1.z + v1.w*v1.w;
    #pragma unroll
    for (int o = 32; o >= 1; o >>= 1) ss += __shfl_xor(ss, o, 64);
    const float sc = 1.0f / fmaxf(sqrtf(ss), EPS_);
    ushort4 w0, w1;
    w0.x = f2bf(v0.x*sc); w0.y = f2bf(v0.y*sc); w0.z = f2bf(v0.z*sc); w0.w = f2bf(v0.w*sc);
    w1.x = f2bf(v1.x*sc); w1.y = f2bf(v1.y*sc); w1.z = f2bf(v1.z*sc); w1.w = f2bf(v1.w*sc);
    *(ushort4*)(nrm + off)     = w0;
    *(ushort4*)(nrm + off + 4) = w1;
}

// ---------------- MFMA sim-GEMM: 128x128/block, dbuf LDS, swizzled -----------
// grid (8, 16, 8); 256 thr = 4 waves, wave (wr,wc) owns a 64x64 quadrant.
// Double-buffered global_load_lds staging with issue-AFTER-barrier ordering:
//   __syncthreads() at loop top waits only the wave's own current-kit DMAs
//   (issued one full iteration earlier -> usually already retired: no drain
//   stall), then kit+1 DMAs go into the other buffer and stay in flight
//   across the next barrier. One barrier per kit.
// LDS tiles [128 rows][64 B]; 16B-chunk XOR swizzle (phys = kq ^ ((row>>1)&3),
// applied on the DMA SOURCE address) -> frag reads are 2-way (free) instead of
// the row-major layout's 8-way conflict.
__global__ __launch_bounds__(256, 4) void loss_kernel(const unsigned short* __restrict__ nrm,
                                                      float* __restrict__ rs_g,
                                                      float* __restrict__ rp_g) {
    const int b  = blockIdx.y;
    const int t0 = blockIdx.x * BM;
    const int j0 = blockIdx.z * BN;
    const char* base = (const char*)(nrm + (size_t)b * T_ * D_);  // row = 1024 B

    __shared__ __align__(16) unsigned short Al[2][BM * 32];   // 2 x 8 KB
    __shared__ __align__(16) unsigned short Bl[2][BN * 32];   // 2 x 8 KB

    const int tid = threadIdx.x;
    const int w   = tid >> 6;
    const int l   = tid & 63;

    // ---- staging addressing: wave w stages rows [w*32, w*32+32) of A and B,
    //      as 2 DMA instrs each (16 rows x 64 B = 1 KB per instr).
    //      lane l: row r = l>>2, phys chunk c = l&3, fetches global chunk
    //      g = c ^ ((r>>1)&3)  (write-side of the XOR swizzle).
    const int r  = l >> 2;
    const int cc = l & 3;
    const int g  = cc ^ ((r >> 1) & 3);
    const char* sA0 = base + (size_t)(t0 + w * 32 +      r) * 1024 + g * 16;
    const char* sA1 = base + (size_t)(t0 + w * 32 + 16 + r) * 1024 + g * 16;
    const char* sB0 = base + (size_t)(j0 + w * 32 +      r) * 1024 + g * 16;
    const char* sB1 = base + (size_t)(j0 + w * 32 + 16 + r) * 1024 + g * 16;

#define ISSUE(P) do {                                             \
    glds16(sA0, (char*)Al[P] + w * 2048);                         \
    glds16(sA1, (char*)Al[P] + w * 2048 + 1024);                  \
    glds16(sB0, (char*)Bl[P] + w * 2048);                         \
    glds16(sB1, (char*)Bl[P] + w * 2048 + 1024);                  \
    sA0 += 64; sA1 += 64; sB0 += 64; sB1 += 64;                   \
} while (0)

    // ---- fragment read addressing (read-side of the swizzle)
    const int wr = w >> 1, wc = w & 1;
    const int m  = l & 15;
    const int kq = l >> 4;
    const int rdsw = (kq ^ ((m >> 1) & 3)) << 4;
    const int raoff = (wr * 64 + m) * 64 + rdsw;   // + mi*1024 per frag group
    const int rboff = (wc * 64 + m) * 64 + rdsw;

    floatx4 acc[4][4] = {};

    ISSUE(0);   // prologue: kit 0 in flight

    #pragma unroll 2
    for (int kit = 0; kit < NKIT; ++kit) {
        __syncthreads();                 // own kit-DMAs done (vmcnt0) + wave sync
        if (kit + 1 < NKIT) ISSUE((kit + 1) & 1);   // prefetch stays in flight

        const char* pa = (const char*)Al[kit & 1] + raoff;
        const char* pb = (const char*)Bl[kit & 1] + rboff;
        short8 af[4], bf[4];
        #pragma unroll
        for (int mi = 0; mi < 4; ++mi) af[mi] = *(const short8*)(pa + mi * 1024);
        #pragma unroll
        for (int ni = 0; ni < 4; ++ni) bf[ni] = *(const short8*)(pb + ni * 1024);

        #pragma unroll
        for (int mi = 0; mi < 4; ++mi)
            #pragma unroll
            for (int ni = 0; ni < 4; ++ni)
                acc[mi][ni] = __builtin_amdgcn_mfma_f32_16x16x32_bf16(
                    af[mi], bf[ni], acc[mi][ni], 0, 0, 0);
    }
#undef ISSUE

    // Epilogue. C/D layout (m89-verified): col = lane&15, row = (lane>>4)*4+reg.
    const int lrow = l >> 4;
    const int lcol = l & 15;
    const int bT   = b * T_;

    #pragma unroll
    for (int mi = 0; mi < 4; ++mi) {
        #pragma unroll
        for (int rg = 0; rg < 4; ++rg) {
            const int t = t0 + wr * 64 + mi * 16 + lrow * 4 + rg;
            float rsum = 0.f, rp = 0.f;
            #pragma unroll
            for (int ni = 0; ni < 4; ++ni) {
                const int j  = j0 + wc * 64 + ni * 16 + lcol;
                const float s2 = acc[mi][ni][rg] * SCALE2;      // base-2 logit
                const float e  = exp2f(s2);
                if (j < t - 1 || j > t + 1) rsum += e;          // negatives only
                if (j == t + 1)             rp   = s2;          // positive logit
            }
            #pragma unroll
            for (int o = 8; o >= 1; o >>= 1) {
                rsum += __shfl_xor(rsum, o, 64);
                rp   += __shfl_xor(rp,   o, 64);
            }
            if (lcol == 0) {
                atomicAdd(&rs_g[bT + t], rsum);
                if (rp != 0.0f) atomicAdd(&rp_g[bT + t], rp);
            }
        }
    }
}

// ---------------- finalize: loss per (b,t), mean (base-2 domain) -------------
__global__ __launch_bounds__(256) void fin_kernel(const float* __restrict__ rs_g,
                                                  const float* __restrict__ rp_g,
                                                  float* __restrict__ out) {
    const int idx = blockIdx.x * 256 + threadIdx.x;
    float v = 0.0f;
    if (idx < B_ * T_) {
        const int t = idx & (T_ - 1);
        if (t >= 1 && t <= T_ - 2) {
            const float p2 = rp_g[idx];           // pos logit * log2e
            const float s  = rs_g[idx];           // sum_neg 2^logit2
            v = (log2f(exp2f(p2) + s) - p2) * LN2_;
        }
    }
    #pragma unroll
    for (int o = 32; o >= 1; o >>= 1) v += __shfl_xor(v, o, 64);
    __shared__ float ws_[4];
    if ((threadIdx.x & 63) == 0) ws_[threadIdx.x >> 6] = v;
    __syncthreads();
    if (threadIdx.x == 0) {
        const float scale = 1.0f / (float)(B_ * (T_ - 2));
        atomicAdd(out, (ws_[0] + ws_[1] + ws_[2] + ws_[3]) * scale);
    }
}

extern "C" void kernel_launch(void* const* d_in, const int* in_sizes, int n_in,
                              void* d_out, int out_size, void* d_ws, size_t ws_size,
                              hipStream_t stream) {
    const float* feat = (const float*)d_in[0];
    float* out = (float*)d_out;

    // ws layout: nrm (bf16, B*T*D ushorts = 16 MB) | rs (B*T f32) | rp (B*T f32)
    unsigned short* nrm = (unsigned short*)d_ws;
    float* rs_g = (float*)((char*)d_ws + (size_t)B_ * T_ * D_ * sizeof(unsigned short));
    float* rp_g = rs_g + B_ * T_;

    norm_kernel<<<B_ * T_ / 4, 256, 0, stream>>>(feat, nrm, rs_g, rp_g, out);
    loss_kernel<<<dim3(T_ / BM, B_, T_ / BN), 256, 0, stream>>>(nrm, rs_g, rp_g);
    fin_kernel<<<(B_ * T_ + 255) / 256, 256, 0, stream>>>(rs_g, rp_g, out);
}

// Round 7
// 101.841 us; speedup vs baseline: 1.4494x; 1.0522x over previous
//
#include <hip/hip_runtime.h>
#include <hip/hip_bf16.h>

// Problem constants (features: (16, 1024, 512) fp32)
#define B_ 16
#define T_ 1024
#define D_ 512
#define EPS_ 1e-8f
#define SCALE2 20.609929155566063f   // (1/0.07) * log2(e): logits in base-2 domain
#define LN2_ 0.6931471805599453f

#define BT 64                        // tile side per wave
#define NB 16                        // T_/BT block-rows per batch
#define NPAIR (NB * (NB + 1) / 2)    // 136 upper-triangle pairs
#define NKIT 16                      // D_/32 K-iterations (BK=32 bf16 = 64 B/row)

typedef __attribute__((ext_vector_type(8))) short short8;   // 8 bf16 = 4 VGPRs
typedef __attribute__((ext_vector_type(4))) float floatx4;

typedef __attribute__((address_space(1))) const unsigned int g_u32;
typedef __attribute__((address_space(3))) unsigned int l_u32;

__device__ __forceinline__ void glds16(const void* g, void* l) {
    __builtin_amdgcn_global_load_lds((g_u32*)g, (l_u32*)l, 16, 0, 0);
}

__device__ __forceinline__ unsigned short f2bf(float x) {
    unsigned u = __float_as_uint(x);
    return (unsigned short)((u + 0x7fffu + ((u >> 16) & 1u)) >> 16);  // RNE
}

// ---------------- row L2-normalize -> bf16, fused zero-init ------------------
__global__ __launch_bounds__(256) void norm_kernel(const float* __restrict__ f,
                                                   unsigned short* __restrict__ nrm,
                                                   float* __restrict__ rs_g,
                                                   float* __restrict__ rp_g,
                                                   float* __restrict__ out) {
    const int gi = blockIdx.x * 256 + threadIdx.x;
    if (gi < B_ * T_) { rs_g[gi] = 0.0f; rp_g[gi] = 0.0f; }
    if (gi == 0) out[0] = 0.0f;

    const int row  = blockIdx.x * 4 + (threadIdx.x >> 6);
    const int lane = threadIdx.x & 63;
    const size_t off = (size_t)row * D_ + lane * 8;
    const float4 v0 = *(const float4*)(f + off);
    const float4 v1 = *(const float4*)(f + off + 4);
    float ss = v0.x*v0.x + v0.y*v0.y + v0.z*v0.z + v0.w*v0.w
             + v1.x*v1.x + v1.y*v1.y + v1.z*v1.z + v1.w*v1.w;
    #pragma unroll
    for (int o = 32; o >= 1; o >>= 1) ss += __shfl_xor(ss, o, 64);
    const float sc = 1.0f / fmaxf(sqrtf(ss), EPS_);
    ushort4 w0, w1;
    w0.x = f2bf(v0.x*sc); w0.y = f2bf(v0.y*sc); w0.z = f2bf(v0.z*sc); w0.w = f2bf(v0.w*sc);
    w1.x = f2bf(v1.x*sc); w1.y = f2bf(v1.y*sc); w1.z = f2bf(v1.z*sc); w1.w = f2bf(v1.w*sc);
    *(ushort4*)(nrm + off)     = w0;
    *(ushort4*)(nrm + off + 4) = w1;
}

// ---------------- MFMA sim-GEMM: symmetric pairs, 1 wave = 64x64 tile --------
// r6's proven machinery (global_load_lds dbuf, issue-after-barrier, XOR chunk
// swizzle) at 1-wave granularity + upper-triangle symmetry (0.53x MFMA work).
// 2176 blocks of 64 threads; the wave privately owns its LDS, so
// __syncthreads() is a cheap wave-local barrier whose vmcnt(0) drains only the
// current kit's DMAs (issued a full iteration earlier -> already retired).
// Off-diagonal tiles also emit column sums (mask |j-t|<=1 is symmetric);
// diagonal tiles skip the B DMA entirely (B tile == A tile).
__global__ __launch_bounds__(64) void loss_kernel(const unsigned short* __restrict__ nrm,
                                                  float* __restrict__ rs_g,
                                                  float* __restrict__ rp_g) {
    const int slot = blockIdx.x & 15;
    int u = blockIdx.x >> 4;                        // pair index 0..135
    const int b = ((slot & 7) << 1) | (slot >> 3);  // XCD-pinned batches
    int bi = 0, rem = NB;
    while (u >= rem) { u -= rem; --rem; ++bi; }
    const int bj   = bi + u;
    const bool diag = (bi == bj);
    const bool near = (bj - bi) <= 1;               // tiles that can hold j==t+1

    const int t0 = bi * BT;
    const int j0 = bj * BT;
    const char* base = (const char*)(nrm + (size_t)b * T_ * D_);  // row = 1024 B

    __shared__ __align__(16) unsigned short Al[2][2048];   // 2 x 4 KB: [64 rows][64 B]
    __shared__ __align__(16) unsigned short Bl[2][2048];   // 2 x 4 KB

    const int l = threadIdx.x & 63;

    // ---- staging (write-side swizzle): lane l -> row r=l>>2 of each 16-row
    //      group, phys chunk c=l&3 fetches global chunk g = c ^ ((r>>1)&3).
    const int r   = l >> 2;
    const int gsw = (l & 3) ^ ((r >> 1) & 3);
    const char* sA[4];
    const char* sB[4];
    #pragma unroll
    for (int i = 0; i < 4; ++i) {
        sA[i] = base + (size_t)(t0 + i * 16 + r) * 1024 + gsw * 16;
        sB[i] = base + (size_t)(j0 + i * 16 + r) * 1024 + gsw * 16;
    }

#define ISSUE(P) do {                                                  \
    _Pragma("unroll")                                                  \
    for (int i_ = 0; i_ < 4; ++i_) {                                   \
        glds16(sA[i_], (char*)Al[P] + i_ * 1024);                      \
        sA[i_] += 64;                                                  \
    }                                                                  \
    if (!diag) {                                                       \
        _Pragma("unroll")                                              \
        for (int i_ = 0; i_ < 4; ++i_) {                               \
            glds16(sB[i_], (char*)Bl[P] + i_ * 1024);                  \
            sB[i_] += 64;                                              \
        }                                                              \
    }                                                                  \
} while (0)

    // ---- fragment reads (read-side swizzle): row m+mi*16, logical chunk kq
    //      lives at phys chunk kq ^ ((m>>1)&3).
    const int m  = l & 15;
    const int kq = l >> 4;
    const int rdoff = m * 64 + ((kq ^ ((m >> 1) & 3)) << 4);   // + mi*1024

    floatx4 acc[4][4] = {};

    ISSUE(0);   // prologue: kit 0 in flight

    #pragma unroll 2
    for (int kit = 0; kit < NKIT; ++kit) {
        __syncthreads();                       // drain own current-kit DMAs
        if (kit + 1 < NKIT) ISSUE((kit + 1) & 1);   // prefetch stays in flight

        const char* pa = (const char*)Al[kit & 1] + rdoff;
        const char* pb = (diag ? (const char*)Al[kit & 1]
                               : (const char*)Bl[kit & 1]) + rdoff;
        short8 af[4], bf[4];
        #pragma unroll
        for (int mi = 0; mi < 4; ++mi) af[mi] = *(const short8*)(pa + mi * 1024);
        #pragma unroll
        for (int ni = 0; ni < 4; ++ni) bf[ni] = *(const short8*)(pb + ni * 1024);

        #pragma unroll
        for (int mi = 0; mi < 4; ++mi)
            #pragma unroll
            for (int ni = 0; ni < 4; ++ni)
                acc[mi][ni] = __builtin_amdgcn_mfma_f32_16x16x32_bf16(
                    af[mi], bf[ni], acc[mi][ni], 0, 0, 0);
    }
#undef ISSUE

    // Epilogue. C/D layout (m89-verified): col = lane&15, row = (lane>>4)*4+reg.
    const int lrow = l >> 4;
    const int lcol = l & 15;
    const int bT   = b * T_;
    float cs[4] = {0.f, 0.f, 0.f, 0.f};   // per-ni column partials (off-diag)

    #pragma unroll
    for (int mi = 0; mi < 4; ++mi) {
        #pragma unroll
        for (int rg = 0; rg < 4; ++rg) {
            const int t = t0 + mi * 16 + lrow * 4 + rg;
            float rsum = 0.f;
            #pragma unroll
            for (int ni = 0; ni < 4; ++ni) {
                const int j  = j0 + ni * 16 + lcol;
                const float s2 = acc[mi][ni][rg] * SCALE2;       // base-2 logit
                const float e  = exp2f(s2);
                if (j < t - 1 || j > t + 1) { rsum += e; cs[ni] += e; }
                if (near && j == t + 1) atomicAdd(&rp_g[bT + t], s2);  // unique owner
            }
            #pragma unroll
            for (int o = 8; o >= 1; o >>= 1) rsum += __shfl_xor(rsum, o, 64);
            if (lcol == 0) atomicAdd(&rs_g[bT + t], rsum);
        }
    }
    if (!diag) {  // column sums: anchors j in J, negatives t in I (mask symmetric)
        #pragma unroll
        for (int ni = 0; ni < 4; ++ni) {
            float c = cs[ni];
            c += __shfl_xor(c, 16, 64);
            c += __shfl_xor(c, 32, 64);
            if (lrow == 0)
                atomicAdd(&rs_g[bT + j0 + ni * 16 + lcol], c);
        }
    }
}

// ---------------- finalize: loss per (b,t), mean (base-2 domain) -------------
__global__ __launch_bounds__(256) void fin_kernel(const float* __restrict__ rs_g,
                                                  const float* __restrict__ rp_g,
                                                  float* __restrict__ out) {
    const int idx = blockIdx.x * 256 + threadIdx.x;
    float v = 0.0f;
    if (idx < B_ * T_) {
        const int t = idx & (T_ - 1);
        if (t >= 1 && t <= T_ - 2) {
            const float p2 = rp_g[idx];           // pos logit * log2e
            const float s  = rs_g[idx];           // sum_neg 2^logit2
            v = (log2f(exp2f(p2) + s) - p2) * LN2_;
        }
    }
    #pragma unroll
    for (int o = 32; o >= 1; o >>= 1) v += __shfl_xor(v, o, 64);
    __shared__ float ws_[4];
    if ((threadIdx.x & 63) == 0) ws_[threadIdx.x >> 6] = v;
    __syncthreads();
    if (threadIdx.x == 0) {
        const float scale = 1.0f / (float)(B_ * (T_ - 2));
        atomicAdd(out, (ws_[0] + ws_[1] + ws_[2] + ws_[3]) * scale);
    }
}

extern "C" void kernel_launch(void* const* d_in, const int* in_sizes, int n_in,
                              void* d_out, int out_size, void* d_ws, size_t ws_size,
                              hipStream_t stream) {
    const float* feat = (const float*)d_in[0];
    float* out = (float*)d_out;

    // ws layout: nrm (bf16, B*T*D ushorts = 16 MB) | rs (B*T f32) | rp (B*T f32)
    unsigned short* nrm = (unsigned short*)d_ws;
    float* rs_g = (float*)((char*)d_ws + (size_t)B_ * T_ * D_ * sizeof(unsigned short));
    float* rp_g = rs_g + B_ * T_;

    norm_kernel<<<B_ * T_ / 4, 256, 0, stream>>>(feat, nrm, rs_g, rp_g, out);
    loss_kernel<<<NPAIR * B_, 64, 0, stream>>>(nrm, rs_g, rp_g);
    fin_kernel<<<(B_ * T_ + 255) / 256, 256, 0, stream>>>(rs_g, rp_g, out);
}

// Round 8
// 101.014 us; speedup vs baseline: 1.4613x; 1.0082x over previous
//
#include <hip/hip_runtime.h>
#include <hip/hip_bf16.h>
#include <hip/hip_fp8.h>

// Problem constants (features: (16, 1024, 512) fp32)
#define B_ 16
#define T_ 1024
#define D_ 512
#define EPS_ 1e-8f
#define SCALE2 20.609929155566063f   // (1/0.07) * log2(e): logits in base-2 domain
#define LN2_ 0.6931471805599453f

#define BT 64                        // tile side per wave
#define NB 16                        // T_/BT block-rows per batch
#define NPAIR (NB * (NB + 1) / 2)    // 136 upper-triangle pairs
#define NKIT 4                       // D_/128 K-iterations (K=128 per MFMA)
#define SCL 0x7B7B7B7B               // E8M0 2^-4 in every byte (opsel-immune)

typedef __attribute__((ext_vector_type(4))) int   int4v;
typedef __attribute__((ext_vector_type(8))) int   int8v;
typedef __attribute__((ext_vector_type(4))) float floatx4;

typedef __attribute__((address_space(1))) const unsigned int g_u32;
typedef __attribute__((address_space(3))) unsigned int l_u32;

__device__ __forceinline__ void glds16(const void* g, void* l) {
    __builtin_amdgcn_global_load_lds((g_u32*)g, (l_u32*)l, 16, 0, 0);
}

__device__ __forceinline__ unsigned char f2e4m3(float x) {
    __hip_fp8_e4m3 q(x);                       // OCP e4m3fn, HW RNE on gfx950
    return (unsigned char)q.__x;
}

// ---------------- row L2-normalize -> fp8 e4m3 (x16), fused zero-init --------
// Stores 16*n_i in e4m3 (elements ~N(0,0.7): clear of subnormal coarseness);
// the MFMA block-scales of 2^-4 * 2^-4 restore the true product.
__global__ __launch_bounds__(256) void norm_kernel(const float* __restrict__ f,
                                                   unsigned char* __restrict__ nrm,
                                                   float* __restrict__ rs_g,
                                                   float* __restrict__ rp_g,
                                                   float* __restrict__ out) {
    const int gi = blockIdx.x * 256 + threadIdx.x;
    if (gi < B_ * T_) { rs_g[gi] = 0.0f; rp_g[gi] = 0.0f; }
    if (gi == 0) out[0] = 0.0f;

    const int row  = blockIdx.x * 4 + (threadIdx.x >> 6);
    const int lane = threadIdx.x & 63;
    const size_t off = (size_t)row * D_ + lane * 8;
    const float4 v0 = *(const float4*)(f + off);
    const float4 v1 = *(const float4*)(f + off + 4);
    float ss = v0.x*v0.x + v0.y*v0.y + v0.z*v0.z + v0.w*v0.w
             + v1.x*v1.x + v1.y*v1.y + v1.z*v1.z + v1.w*v1.w;
    #pragma unroll
    for (int o = 32; o >= 1; o >>= 1) ss += __shfl_xor(ss, o, 64);
    const float sc = 16.0f / fmaxf(sqrtf(ss), EPS_);   // pre-scale by 16
    unsigned int w0 =  (unsigned int)f2e4m3(v0.x*sc)
                    | ((unsigned int)f2e4m3(v0.y*sc) << 8)
                    | ((unsigned int)f2e4m3(v0.z*sc) << 16)
                    | ((unsigned int)f2e4m3(v0.w*sc) << 24);
    unsigned int w1 =  (unsigned int)f2e4m3(v1.x*sc)
                    | ((unsigned int)f2e4m3(v1.y*sc) << 8)
                    | ((unsigned int)f2e4m3(v1.z*sc) << 16)
                    | ((unsigned int)f2e4m3(v1.w*sc) << 24);
    uint2 w; w.x = w0; w.y = w1;
    *(uint2*)(nrm + (size_t)row * D_ + lane * 8) = w;   // 8 fp8 bytes/lane
}

// ---------------- MX-fp8 MFMA sim-GEMM: symmetric pairs, 1 wave = 64x64 ------
// r7's proven machinery (global_load_lds ring, issue-after-barrier, XOR chunk
// swizzle on [64 rows][64 B] stages) with mfma_scale_f32_16x16x128_f8f6f4.
// 8 K-stages of 64 fp8; kit j consumes stages 2j,2j+1 (K=128) from a 4-slot
// ring and prefetches stages 2j+2,2j+3. Both block-scales = 2^-4 (data x16).
// A-frag layout (bf16-pattern extension): lane kq*16+m holds row m,
// k in [kq*32, kq*32+32) contiguous bytes. C/D layout: shape-determined,
// identical to bf16 16x16 (col=lane&15, row=(lane>>4)*4+reg) -> epilogue reused.
__global__ __launch_bounds__(64) void loss_kernel(const unsigned char* __restrict__ nrm,
                                                  float* __restrict__ rs_g,
                                                  float* __restrict__ rp_g) {
    const int slot = blockIdx.x & 15;
    int u = blockIdx.x >> 4;                        // pair index 0..135
    const int b = ((slot & 7) << 1) | (slot >> 3);  // XCD-pinned batches
    int bi = 0, rem = NB;
    while (u >= rem) { u -= rem; --rem; ++bi; }
    const int bj   = bi + u;
    const bool diag = (bi == bj);
    const bool near = (bj - bi) <= 1;               // tiles that can hold j==t+1

    const int t0 = bi * BT;
    const int j0 = bj * BT;
    const char* base = (const char*)(nrm + (size_t)b * T_ * D_);  // row = 512 B

    __shared__ __align__(16) char Ar[4][4096];   // 4-slot ring: [64 rows][64 B]
    __shared__ __align__(16) char Br[4][4096];

    const int l = threadIdx.x & 63;
    const int m = l & 15;

    // ---- staging (write-side swizzle, r7-identical): lane l -> row r=l>>2 of
    //      each 16-row group, phys chunk l&3 fetches global chunk (l&3)^((r>>1)&3)
    const int r   = l >> 2;
    const int gsw = (l & 3) ^ ((r >> 1) & 3);
    const char* sA[4];
    const char* sB[4];
    #pragma unroll
    for (int i = 0; i < 4; ++i) {
        sA[i] = base + (size_t)(t0 + i * 16 + r) * 512 + gsw * 16;
        sB[i] = base + (size_t)(j0 + i * 16 + r) * 512 + gsw * 16;
    }

    // issue stage S (64 B of K) into ring slot S&3
#define ISSUE(S) do {                                                  \
    _Pragma("unroll")                                                  \
    for (int i_ = 0; i_ < 4; ++i_)                                     \
        glds16(sA[i_] + (S) * 64, Ar[(S) & 3] + i_ * 1024);            \
    if (!diag) {                                                       \
        _Pragma("unroll")                                              \
        for (int i_ = 0; i_ < 4; ++i_)                                 \
            glds16(sB[i_] + (S) * 64, Br[(S) & 3] + i_ * 1024);        \
    }                                                                  \
} while (0)

    // ---- fragment reads (read-side swizzle): lane (m, kq=l>>4) reads 32 B of
    //      row m' from stage 2j+(kq>>1): logical chunks 2*(kq&1), +1, each XOR
    //      key (m>>1)&3. Two b128 per frag.
    const int kqh  = l >> 5;                       // stage select within kit
    const int ph0  = (2 * ((l >> 4) & 1)) ^ ((m >> 1) & 3);
    const int rd0  = m * 64 + ph0 * 16;
    const int rd1  = m * 64 + (ph0 ^ 1) * 16;

    floatx4 acc[4][4] = {};

    ISSUE(0); ISSUE(1);   // prologue: kit 0's two stages in flight

    #pragma unroll
    for (int j = 0; j < NKIT; ++j) {
        __syncthreads();                 // drain own current-kit DMAs
        if (j < NKIT - 1) { ISSUE(2 * j + 2); ISSUE(2 * j + 3); }

        const char* As = Ar[(2 * j + kqh) & 3];
        const char* Bs = diag ? Ar[(2 * j + kqh) & 3] : Br[(2 * j + kqh) & 3];
        int8v af[4], bf[4];
        #pragma unroll
        for (int mi = 0; mi < 4; ++mi) {
            int4v lo = *(const int4v*)(As + mi * 1024 + rd0);
            int4v hi = *(const int4v*)(As + mi * 1024 + rd1);
            af[mi] = __builtin_shufflevector(lo, hi, 0, 1, 2, 3, 4, 5, 6, 7);
        }
        #pragma unroll
        for (int ni = 0; ni < 4; ++ni) {
            int4v lo = *(const int4v*)(Bs + ni * 1024 + rd0);
            int4v hi = *(const int4v*)(Bs + ni * 1024 + rd1);
            bf[ni] = __builtin_shufflevector(lo, hi, 0, 1, 2, 3, 4, 5, 6, 7);
        }

        #pragma unroll
        for (int mi = 0; mi < 4; ++mi)
            #pragma unroll
            for (int ni = 0; ni < 4; ++ni)
                acc[mi][ni] = __builtin_amdgcn_mfma_scale_f32_16x16x128_f8f6f4(
                    af[mi], bf[ni], acc[mi][ni],
                    0, 0,              // cbsz=fp8(e4m3), blgp=fp8(e4m3)
                    0, SCL,            // opsel_a, scale_a (2^-4 every byte)
                    0, SCL);           // opsel_b, scale_b
    }
#undef ISSUE

    // Epilogue. C/D layout (shape-determined, m89/m121-128): col = lane&15,
    // row = (lane>>4)*4 + reg. Identical to the verified bf16 epilogue.
    const int lrow = l >> 4;
    const int lcol = l & 15;
    const int bT   = b * T_;
    float cs[4] = {0.f, 0.f, 0.f, 0.f};   // per-ni column partials (off-diag)

    #pragma unroll
    for (int mi = 0; mi < 4; ++mi) {
        #pragma unroll
        for (int rg = 0; rg < 4; ++rg) {
            const int t = t0 + mi * 16 + lrow * 4 + rg;
            float rsum = 0.f;
            #pragma unroll
            for (int ni = 0; ni < 4; ++ni) {
                const int j  = j0 + ni * 16 + lcol;
                const float s2 = acc[mi][ni][rg] * SCALE2;       // base-2 logit
                const float e  = exp2f(s2);
                if (j < t - 1 || j > t + 1) { rsum += e; cs[ni] += e; }
                if (near && j == t + 1) atomicAdd(&rp_g[bT + t], s2);  // unique owner
            }
            #pragma unroll
            for (int o = 8; o >= 1; o >>= 1) rsum += __shfl_xor(rsum, o, 64);
            if (lcol == 0) atomicAdd(&rs_g[bT + t], rsum);
        }
    }
    if (!diag) {  // column sums: anchors j in J, negatives t in I (mask symmetric)
        #pragma unroll
        for (int ni = 0; ni < 4; ++ni) {
            float c = cs[ni];
            c += __shfl_xor(c, 16, 64);
            c += __shfl_xor(c, 32, 64);
            if (lrow == 0)
                atomicAdd(&rs_g[bT + j0 + ni * 16 + lcol], c);
        }
    }
}

// ---------------- finalize: loss per (b,t), mean (base-2 domain) -------------
__global__ __launch_bounds__(256) void fin_kernel(const float* __restrict__ rs_g,
                                                  const float* __restrict__ rp_g,
                                                  float* __restrict__ out) {
    const int idx = blockIdx.x * 256 + threadIdx.x;
    float v = 0.0f;
    if (idx < B_ * T_) {
        const int t = idx & (T_ - 1);
        if (t >= 1 && t <= T_ - 2) {
            const float p2 = rp_g[idx];           // pos logit * log2e
            const float s  = rs_g[idx];           // sum_neg 2^logit2
            v = (log2f(exp2f(p2) + s) - p2) * LN2_;
        }
    }
    #pragma unroll
    for (int o = 32; o >= 1; o >>= 1) v += __shfl_xor(v, o, 64);
    __shared__ float ws_[4];
    if ((threadIdx.x & 63) == 0) ws_[threadIdx.x >> 6] = v;
    __syncthreads();
    if (threadIdx.x == 0) {
        const float scale = 1.0f / (float)(B_ * (T_ - 2));
        atomicAdd(out, (ws_[0] + ws_[1] + ws_[2] + ws_[3]) * scale);
    }
}

extern "C" void kernel_launch(void* const* d_in, const int* in_sizes, int n_in,
                              void* d_out, int out_size, void* d_ws, size_t ws_size,
                              hipStream_t stream) {
    const float* feat = (const float*)d_in[0];
    float* out = (float*)d_out;

    // ws layout: nrm (fp8, B*T*D bytes = 8 MB) | rs (B*T f32) | rp (B*T f32)
    unsigned char* nrm = (unsigned char*)d_ws;
    float* rs_g = (float*)((char*)d_ws + (size_t)B_ * T_ * D_);
    float* rp_g = rs_g + B_ * T_;

    norm_kernel<<<B_ * T_ / 4, 256, 0, stream>>>(feat, nrm, rs_g, rp_g, out);
    loss_kernel<<<NPAIR * B_, 64, 0, stream>>>(nrm, rs_g, rp_g);
    fin_kernel<<<(B_ * T_ + 255) / 256, 256, 0, stream>>>(rs_g, rp_g, out);
}